// Round 1
// baseline (296.983 us; speedup 1.0000x reference)
//
#include <hip/hip_runtime.h>
#include <stdint.h>
#include <stddef.h>

#define NB 8
#define NC 512
#define NL 64
#define NN 6272
#define NT 64
#define NTILES (NN / NT)   // 98

typedef short bf16x8 __attribute__((ext_vector_type(8)));
typedef float f32x4 __attribute__((ext_vector_type(4)));

__device__ __forceinline__ unsigned short f2bf(float f) {
    uint32_t u = __float_as_uint(f);
    u += 0x7fffu + ((u >> 16) & 1u);
    return (unsigned short)(u >> 16);
}
__device__ __forceinline__ float bf2f(unsigned short s) {
    return __uint_as_float(((uint32_t)s) << 16);
}

// ---------------------------------------------------------------------------
// Kernel A: per (b, n-tile): a1 = relu(BN(W @ Ktile)); sumsq_l += |a1_l|^2;
//           latent_unnorm[b] += a1 @ Ktile^T   (atomics)
// LDS: Knc[64][520] bf16 (66560) | Kcn[512][72] bf16 (73728) | A1[64][72] (9216)
//      | scale[64] f32 | shift[64] f32   => 150016 bytes
// ---------------------------------------------------------------------------
__global__ __launch_bounds__(512, 2)
void kA(const float* __restrict__ key, const float* __restrict__ phi_w,
        const float* __restrict__ gma, const float* __restrict__ bta,
        const float* __restrict__ mu, const float* __restrict__ var,
        float* __restrict__ latu, float* __restrict__ ssq) {
    extern __shared__ char smem[];
    unsigned short* Knc = (unsigned short*)smem;                 // [NT][520]
    unsigned short* Kcn = (unsigned short*)(smem + 66560);       // [NC][72]
    unsigned short* A1  = (unsigned short*)(smem + 140288);      // [NL][72]
    float* sc = (float*)(smem + 149504);
    float* sh = sc + NL;

    const int tid = threadIdx.x;
    const int b   = blockIdx.y;
    const int n0  = blockIdx.x * NT;

    if (tid < NL) {
        float s = gma[tid] * rsqrtf(var[tid] + 1e-5f);
        sc[tid] = s;
        sh[tid] = bta[tid] - mu[tid] * s;
    }

    // ---- stage K tile (coalesced f32 reads -> bf16 in two LDS layouts) ----
    const float* kp = key + (size_t)b * NC * NN + n0;
    for (int idx = tid; idx < NC * (NT / 4); idx += 512) {
        int c = idx >> 4;           // NT/4 = 16 float4 per row
        int j = (idx & 15) << 2;    // n offset in tile
        float4 v = *(const float4*)(kp + (size_t)c * NN + j);
        unsigned short b0 = f2bf(v.x), b1 = f2bf(v.y), b2 = f2bf(v.z), b3 = f2bf(v.w);
        uint32_t* dst = (uint32_t*)&Kcn[c * 72 + j];
        dst[0] = (uint32_t)b0 | ((uint32_t)b1 << 16);
        dst[1] = (uint32_t)b2 | ((uint32_t)b3 << 16);
        Knc[(j + 0) * 520 + c] = b0;
        Knc[(j + 1) * 520 + c] = b1;
        Knc[(j + 2) * 520 + c] = b2;
        Knc[(j + 3) * 520 + c] = b3;
    }
    __syncthreads();

    const int w = tid >> 6;
    const int lane = tid & 63;
    const int q = lane >> 4;
    const int r = lane & 15;
    const f32x4 fz = {0.f, 0.f, 0.f, 0.f};

    // ---- GEMM1: a1[l][n] = W(64x512) @ Ktile(512x64) ----
    {
        const int l0  = (w & 3) * 16;
        const int nc0 = (w >> 2) * 32;
        f32x4 acc0 = fz, acc1 = fz;
        for (int kc = 0; kc < NC; kc += 32) {
            const float* wp = phi_w + (size_t)(l0 + r) * NC + kc + q * 8;
            float4 wa = *(const float4*)wp;
            float4 wb = *(const float4*)(wp + 4);
            bf16x8 af;
            af[0] = (short)f2bf(wa.x); af[1] = (short)f2bf(wa.y);
            af[2] = (short)f2bf(wa.z); af[3] = (short)f2bf(wa.w);
            af[4] = (short)f2bf(wb.x); af[5] = (short)f2bf(wb.y);
            af[6] = (short)f2bf(wb.z); af[7] = (short)f2bf(wb.w);
            bf16x8 b0 = *(const bf16x8*)&Knc[(nc0 + r) * 520 + kc + q * 8];
            bf16x8 b1 = *(const bf16x8*)&Knc[(nc0 + 16 + r) * 520 + kc + q * 8];
            acc0 = __builtin_amdgcn_mfma_f32_16x16x32_bf16(af, b0, acc0, 0, 0, 0);
            acc1 = __builtin_amdgcn_mfma_f32_16x16x32_bf16(af, b1, acc1, 0, 0, 0);
        }
        float ss[4];
        #pragma unroll
        for (int i = 0; i < 4; i++) {
            int l = l0 + q * 4 + i;
            float scl = sc[l], shf = sh[l];
            float v0 = fmaxf(acc0[i] * scl + shf, 0.f);
            float v1 = fmaxf(acc1[i] * scl + shf, 0.f);
            A1[l * 72 + nc0 + r]      = f2bf(v0);
            A1[l * 72 + nc0 + 16 + r] = f2bf(v1);
            ss[i] = v0 * v0 + v1 * v1;
        }
        #pragma unroll
        for (int i = 0; i < 4; i++) {
            float s = ss[i];
            s += __shfl_xor(s, 1);
            s += __shfl_xor(s, 2);
            s += __shfl_xor(s, 4);
            s += __shfl_xor(s, 8);
            if (r == 0) atomicAdd(&ssq[b * NL + l0 + q * 4 + i], s);
        }
    }
    __syncthreads();

    // ---- GEMM2: latu[l][c] += a1(64xNT) @ Ktile^T(NTx512) ----
    {
        const int c0 = w * 64;
        f32x4 acc[4][4];
        #pragma unroll
        for (int fm = 0; fm < 4; fm++)
            #pragma unroll
            for (int fc = 0; fc < 4; fc++) acc[fm][fc] = fz;
        #pragma unroll
        for (int kn = 0; kn < NT; kn += 32) {
            bf16x8 a[4];
            #pragma unroll
            for (int fm = 0; fm < 4; fm++)
                a[fm] = *(const bf16x8*)&A1[(fm * 16 + r) * 72 + kn + q * 8];
            #pragma unroll
            for (int fc = 0; fc < 4; fc++) {
                bf16x8 bb = *(const bf16x8*)&Kcn[(c0 + fc * 16 + r) * 72 + kn + q * 8];
                #pragma unroll
                for (int fm = 0; fm < 4; fm++)
                    acc[fm][fc] = __builtin_amdgcn_mfma_f32_16x16x32_bf16(a[fm], bb, acc[fm][fc], 0, 0, 0);
            }
        }
        float* lp = latu + (size_t)b * NL * NC;
        #pragma unroll
        for (int fm = 0; fm < 4; fm++)
            #pragma unroll
            for (int fc = 0; fc < 4; fc++)
                #pragma unroll
                for (int i = 0; i < 4; i++) {
                    int l = fm * 16 + q * 4 + i;
                    int c = c0 + fc * 16 + r;
                    atomicAdd(&lp[l * NC + c], acc[fm][fc][i]);
                }
    }
}

// ---------------------------------------------------------------------------
// Kernel B (one block per b): latent = latu/||.||_N ; ln = l2norm rows;
// aff = softmax(ln ln^T); latent2 = aff @ latent -> lat2T[b][c][l] bf16
// LDS: Lb[64][520] bf16 | Lt[512][72] bf16 | aff[64][68] f32 | inv_nl[64] | s_c[64]
//      => 158208 bytes
// ---------------------------------------------------------------------------
__global__ __launch_bounds__(256, 1)
void kB(const float* __restrict__ latu, const float* __restrict__ ssq,
        unsigned short* __restrict__ lat2T) {
    extern __shared__ char smem[];
    unsigned short* Lb = (unsigned short*)smem;             // [64][520]
    unsigned short* Lt = (unsigned short*)(smem + 66560);   // [512][72]
    float* aff = (float*)(smem + 140288);                   // [64][68]
    float* inv_nl = (float*)(smem + 157696);
    float* s_c = inv_nl + 64;

    const int tid = threadIdx.x;
    const int b = blockIdx.x;

    if (tid < 64) {
        float s = ssq[b * NL + tid];
        inv_nl[tid] = 1.f / fmaxf(sqrtf(s), 1e-12f);
    }
    __syncthreads();

    const float* lu = latu + (size_t)b * NL * NC;
    for (int idx = tid; idx < NL * (NC / 4); idx += 256) {
        int l = idx >> 7;
        int c = (idx & 127) << 2;
        float4 v = *(const float4*)(lu + l * NC + c);
        float inv = inv_nl[l];
        unsigned short b0 = f2bf(v.x * inv), b1 = f2bf(v.y * inv);
        unsigned short b2 = f2bf(v.z * inv), b3 = f2bf(v.w * inv);
        uint32_t* d = (uint32_t*)&Lb[l * 520 + c];
        d[0] = (uint32_t)b0 | ((uint32_t)b1 << 16);
        d[1] = (uint32_t)b2 | ((uint32_t)b3 << 16);
        Lt[(c + 0) * 72 + l] = b0;
        Lt[(c + 1) * 72 + l] = b1;
        Lt[(c + 2) * 72 + l] = b2;
        Lt[(c + 3) * 72 + l] = b3;
    }
    __syncthreads();

    // row norms of latent (over C)
    {
        int l = tid >> 2, p = tid & 3;
        float s = 0.f;
        for (int c = p * 128; c < p * 128 + 128; c += 4) {
            const unsigned short* d = &Lb[l * 520 + c];
            float v0 = bf2f(d[0]), v1 = bf2f(d[1]), v2 = bf2f(d[2]), v3 = bf2f(d[3]);
            s += v0 * v0 + v1 * v1 + v2 * v2 + v3 * v3;
        }
        s += __shfl_xor(s, 1);
        s += __shfl_xor(s, 2);
        if (p == 0) s_c[l] = 1.f / fmaxf(sqrtf(s), 1e-12f);
    }
    __syncthreads();

    const int w = tid >> 6, lane = tid & 63, q = lane >> 4, r = lane & 15;
    const f32x4 fz = {0.f, 0.f, 0.f, 0.f};

    // G = lat @ lat^T -> logits into aff
    {
        f32x4 g[4];
        #pragma unroll
        for (int fm = 0; fm < 4; fm++) g[fm] = fz;
        for (int kc = 0; kc < NC; kc += 32) {
            bf16x8 a = *(const bf16x8*)&Lb[(w * 16 + r) * 520 + kc + q * 8];
            #pragma unroll
            for (int fm = 0; fm < 4; fm++) {
                bf16x8 bb = *(const bf16x8*)&Lb[(fm * 16 + r) * 520 + kc + q * 8];
                g[fm] = __builtin_amdgcn_mfma_f32_16x16x32_bf16(a, bb, g[fm], 0, 0, 0);
            }
        }
        #pragma unroll
        for (int fm = 0; fm < 4; fm++)
            #pragma unroll
            for (int i = 0; i < 4; i++) {
                int l = w * 16 + q * 4 + i;
                int m = fm * 16 + r;
                aff[l * 68 + m] = g[fm][i] * s_c[l] * s_c[m];
            }
    }
    __syncthreads();

    // softmax over rows of aff (4 threads per row)
    {
        int l = tid >> 2, p = tid & 3;
        float e[16];
        float mx = -1e30f;
        #pragma unroll
        for (int k = 0; k < 16; k++) mx = fmaxf(mx, aff[l * 68 + p * 16 + k]);
        mx = fmaxf(mx, __shfl_xor(mx, 1));
        mx = fmaxf(mx, __shfl_xor(mx, 2));
        float s = 0.f;
        #pragma unroll
        for (int k = 0; k < 16; k++) { e[k] = __expf(aff[l * 68 + p * 16 + k] - mx); s += e[k]; }
        s += __shfl_xor(s, 1);
        s += __shfl_xor(s, 2);
        float invs = 1.f / s;
        __syncthreads();   // ensure all reads of logits done before overwrite
        #pragma unroll
        for (int k = 0; k < 16; k++) aff[l * 68 + p * 16 + k] = e[k] * invs;
    }
    __syncthreads();

    // latent2 = aff(64x64) @ lat(64x512); write lat2T[b][c][l] bf16
    {
        f32x4 acc[4][8];
        #pragma unroll
        for (int fm = 0; fm < 4; fm++)
            #pragma unroll
            for (int fc = 0; fc < 8; fc++) acc[fm][fc] = fz;
        #pragma unroll
        for (int km = 0; km < 64; km += 32) {
            bf16x8 a[4];
            #pragma unroll
            for (int fm = 0; fm < 4; fm++) {
                const float* ap = &aff[(fm * 16 + r) * 68 + km + q * 8];
                float4 x = *(const float4*)ap;
                float4 y = *(const float4*)(ap + 4);
                bf16x8 t;
                t[0] = (short)f2bf(x.x); t[1] = (short)f2bf(x.y);
                t[2] = (short)f2bf(x.z); t[3] = (short)f2bf(x.w);
                t[4] = (short)f2bf(y.x); t[5] = (short)f2bf(y.y);
                t[6] = (short)f2bf(y.z); t[7] = (short)f2bf(y.w);
                a[fm] = t;
            }
            #pragma unroll
            for (int fc = 0; fc < 8; fc++) {
                bf16x8 bb = *(const bf16x8*)&Lt[(w * 128 + fc * 16 + r) * 72 + km + q * 8];
                #pragma unroll
                for (int fm = 0; fm < 4; fm++)
                    acc[fm][fc] = __builtin_amdgcn_mfma_f32_16x16x32_bf16(a[fm], bb, acc[fm][fc], 0, 0, 0);
            }
        }
        unsigned short* out = lat2T + (size_t)b * NC * NL;
        #pragma unroll
        for (int fm = 0; fm < 4; fm++)
            #pragma unroll
            for (int fc = 0; fc < 8; fc++)
                #pragma unroll
                for (int i = 0; i < 4; i++) {
                    int l = fm * 16 + q * 4 + i;
                    int c = w * 128 + fc * 16 + r;
                    out[c * 64 + l] = f2bf(acc[fm][fc][i]);
                }
    }
}

// ---------------------------------------------------------------------------
// Kernel C: per (b, n-tile): a2 = relu(BN(Wp @ Qtile)); col-l2norm over L;
//           out[c][n] = latent2^T(512x64) @ a2(64xNT)
// LDS: Qnc[64][520] bf16 (66560) | A2T[64][72] bf16 (9216) | sc/sh => 76288 B
// ---------------------------------------------------------------------------
__global__ __launch_bounds__(256, 2)
void kC(const float* __restrict__ query, const float* __restrict__ phip_w,
        const float* __restrict__ gma, const float* __restrict__ bta,
        const float* __restrict__ mu, const float* __restrict__ var,
        const unsigned short* __restrict__ lat2T, float* __restrict__ out) {
    extern __shared__ char smem[];
    unsigned short* Qnc = (unsigned short*)smem;             // [NT][520]
    unsigned short* A2T = (unsigned short*)(smem + 66560);   // [NT][72]
    float* sc = (float*)(smem + 75776);
    float* sh = sc + NL;

    const int tid = threadIdx.x;
    const int b = blockIdx.y;
    const int n0 = blockIdx.x * NT;

    if (tid < NL) {
        float s = gma[tid] * rsqrtf(var[tid] + 1e-5f);
        sc[tid] = s;
        sh[tid] = bta[tid] - mu[tid] * s;
    }

    const float* qp = query + (size_t)b * NC * NN + n0;
    for (int idx = tid; idx < NC * (NT / 4); idx += 256) {
        int c = idx >> 4;
        int j = (idx & 15) << 2;
        float4 v = *(const float4*)(qp + (size_t)c * NN + j);
        Qnc[(j + 0) * 520 + c] = f2bf(v.x);
        Qnc[(j + 1) * 520 + c] = f2bf(v.y);
        Qnc[(j + 2) * 520 + c] = f2bf(v.z);
        Qnc[(j + 3) * 520 + c] = f2bf(v.w);
    }
    __syncthreads();

    const int w = tid >> 6, lane = tid & 63, q = lane >> 4, r = lane & 15;
    const f32x4 fz = {0.f, 0.f, 0.f, 0.f};

    // GEMM1: a2T[n][l] = Qtile^T @ Wp^T ; wave w: n rows [w*16, w*16+16)
    {
        f32x4 acc[4];
        #pragma unroll
        for (int fl = 0; fl < 4; fl++) acc[fl] = fz;
        float scv[4], shv[4];
        #pragma unroll
        for (int fl = 0; fl < 4; fl++) { scv[fl] = sc[fl * 16 + r]; shv[fl] = sh[fl * 16 + r]; }
        for (int kc = 0; kc < NC; kc += 32) {
            bf16x8 a = *(const bf16x8*)&Qnc[(w * 16 + r) * 520 + kc + q * 8];
            #pragma unroll
            for (int fl = 0; fl < 4; fl++) {
                const float* wp = phip_w + (size_t)(fl * 16 + r) * NC + kc + q * 8;
                float4 x = *(const float4*)wp;
                float4 y = *(const float4*)(wp + 4);
                bf16x8 t;
                t[0] = (short)f2bf(x.x); t[1] = (short)f2bf(x.y);
                t[2] = (short)f2bf(x.z); t[3] = (short)f2bf(x.w);
                t[4] = (short)f2bf(y.x); t[5] = (short)f2bf(y.y);
                t[6] = (short)f2bf(y.z); t[7] = (short)f2bf(y.w);
                acc[fl] = __builtin_amdgcn_mfma_f32_16x16x32_bf16(a, t, acc[fl], 0, 0, 0);
            }
        }
        float v[4][4];
        float ssum[4] = {0.f, 0.f, 0.f, 0.f};
        #pragma unroll
        for (int fl = 0; fl < 4; fl++)
            #pragma unroll
            for (int i = 0; i < 4; i++) {
                float x = fmaxf(acc[fl][i] * scv[fl] + shv[fl], 0.f);
                v[fl][i] = x;
                ssum[i] += x * x;
            }
        #pragma unroll
        for (int i = 0; i < 4; i++) {
            float s = ssum[i];
            s += __shfl_xor(s, 1);
            s += __shfl_xor(s, 2);
            s += __shfl_xor(s, 4);
            s += __shfl_xor(s, 8);
            float inv = 1.f / fmaxf(sqrtf(s), 1e-12f);
            int n = w * 16 + q * 4 + i;
            #pragma unroll
            for (int fl = 0; fl < 4; fl++)
                A2T[n * 72 + fl * 16 + r] = f2bf(v[fl][i] * inv);
        }
    }
    __syncthreads();

    // GEMM3: out[c][n] = lat2T(512x64) @ a2(64xNT)
    const unsigned short* Ab = lat2T + (size_t)b * NC * NL;
    float* op = out + (size_t)b * NC * NN + n0;
    for (int half = 0; half < 2; half++) {
        int cb = w * 128 + half * 64;
        f32x4 acc[4][4];
        #pragma unroll
        for (int fm = 0; fm < 4; fm++)
            #pragma unroll
            for (int fn = 0; fn < 4; fn++) acc[fm][fn] = fz;
        #pragma unroll
        for (int kl = 0; kl < 64; kl += 32) {
            bf16x8 a[4];
            #pragma unroll
            for (int fm = 0; fm < 4; fm++)
                a[fm] = *(const bf16x8*)&Ab[(size_t)(cb + fm * 16 + r) * 64 + kl + q * 8];
            #pragma unroll
            for (int fn = 0; fn < 4; fn++) {
                bf16x8 bb = *(const bf16x8*)&A2T[(fn * 16 + r) * 72 + kl + q * 8];
                #pragma unroll
                for (int fm = 0; fm < 4; fm++)
                    acc[fm][fn] = __builtin_amdgcn_mfma_f32_16x16x32_bf16(a[fm], bb, acc[fm][fn], 0, 0, 0);
            }
        }
        #pragma unroll
        for (int fm = 0; fm < 4; fm++)
            #pragma unroll
            for (int fn = 0; fn < 4; fn++)
                #pragma unroll
                for (int i = 0; i < 4; i++) {
                    int c = cb + fm * 16 + q * 4 + i;
                    int n = fn * 16 + r;
                    op[(size_t)c * NN + n] = acc[fm][fn][i];
                }
    }
}

// ---------------------------------------------------------------------------
extern "C" void kernel_launch(void* const* d_in, const int* in_sizes, int n_in,
                              void* d_out, int out_size, void* d_ws, size_t ws_size,
                              hipStream_t stream) {
    (void)in_sizes; (void)n_in; (void)out_size; (void)ws_size;
    const float* query = (const float*)d_in[0];
    const float* key   = (const float*)d_in[1];
    const float* phi_w = (const float*)d_in[2];
    const float* phi_g = (const float*)d_in[3];
    const float* phi_b = (const float*)d_in[4];
    const float* phi_m = (const float*)d_in[5];
    const float* phi_v = (const float*)d_in[6];
    const float* php_w = (const float*)d_in[7];
    const float* php_g = (const float*)d_in[8];
    const float* php_b = (const float*)d_in[9];
    const float* php_m = (const float*)d_in[10];
    const float* php_v = (const float*)d_in[11];
    float* out = (float*)d_out;

    char* ws = (char*)d_ws;
    float* latu = (float*)ws;                                  // 8*64*512*4 = 1048576 B
    float* ssq  = (float*)(ws + 1048576);                      // 8*64*4 = 2048 B
    unsigned short* lat2T = (unsigned short*)(ws + 1050624);   // 8*512*64*2 = 524288 B

    hipFuncSetAttribute((const void*)kA, hipFuncAttributeMaxDynamicSharedMemorySize, 150016);
    hipFuncSetAttribute((const void*)kB, hipFuncAttributeMaxDynamicSharedMemorySize, 158208);
    hipFuncSetAttribute((const void*)kC, hipFuncAttributeMaxDynamicSharedMemorySize, 76288);

    hipMemsetAsync(d_ws, 0, 1050624 + 2048, stream);

    dim3 grid(NTILES, NB);
    kA<<<grid, 512, 150016, stream>>>(key, phi_w, phi_g, phi_b, phi_m, phi_v, latu, ssq);
    kB<<<dim3(NB), 256, 158208, stream>>>(latu, ssq, lat2T);
    kC<<<grid, 256, 76288, stream>>>(query, php_w, php_g, php_b, php_m, php_v, lat2T, out);
}

// Round 2
// 210.550 us; speedup vs baseline: 1.4105x; 1.4105x over previous
//
#include <hip/hip_runtime.h>
#include <stdint.h>
#include <stddef.h>

#define NB 8
#define NC 512
#define NL 64
#define NN 6272
#define NT 64
#define NTILES (NN / NT)   // 98
#define NCHUNK 14          // kA chunks per b (448 columns each)
#define NSUB 7             // sub-tiles of 64 per chunk

typedef short bf16x8 __attribute__((ext_vector_type(8)));
typedef float f32x4 __attribute__((ext_vector_type(4)));

__device__ __forceinline__ unsigned short f2bf(float f) {
    uint32_t u = __float_as_uint(f);
    u += 0x7fffu + ((u >> 16) & 1u);
    return (unsigned short)(u >> 16);
}
__device__ __forceinline__ float bf2f(unsigned short s) {
    return __uint_as_float(((uint32_t)s) << 16);
}

// ---------------------------------------------------------------------------
// Kernel A: per (b, 448-wide n-chunk), loop 7 sub-tiles of 64:
//   a1 = relu(BN(W @ Ktile)); ssq_acc += |a1|^2 (regs);
//   acc2 += a1 @ Ktile^T  (regs, across sub-tiles)
// Epilogue: ONE plain f32 partial store per block (no latu atomics).
// LDS: Knc[64][520] bf16 | Kcn[512][72] bf16 | A1[64][72] bf16 | sc/sh
// ---------------------------------------------------------------------------
__global__ __launch_bounds__(512, 2)
void kA(const float* __restrict__ key, const float* __restrict__ phi_w,
        const float* __restrict__ gma, const float* __restrict__ bta,
        const float* __restrict__ mu, const float* __restrict__ var,
        float* __restrict__ part, float* __restrict__ ssq) {
    extern __shared__ char smem[];
    unsigned short* Knc = (unsigned short*)smem;                 // [NT][520]
    unsigned short* Kcn = (unsigned short*)(smem + 66560);       // [NC][72]
    unsigned short* A1  = (unsigned short*)(smem + 140288);      // [NL][72]
    float* sc = (float*)(smem + 149504);
    float* sh = sc + NL;

    const int tid   = threadIdx.x;
    const int b     = blockIdx.y;
    const int chunk = blockIdx.x;
    const int n0    = chunk * (NSUB * NT);

    if (tid < NL) {
        float s = gma[tid] * rsqrtf(var[tid] + 1e-5f);
        sc[tid] = s;
        sh[tid] = bta[tid] - mu[tid] * s;
    }

    const int w = tid >> 6;
    const int lane = tid & 63;
    const int q = lane >> 4;
    const int r = lane & 15;
    const f32x4 fz = {0.f, 0.f, 0.f, 0.f};
    const int l0  = (w & 3) * 16;
    const int nc0 = (w >> 2) * 32;
    const int c0  = w * 64;

    // hoist phi_w fragments (reused by all 7 sub-tiles)
    bf16x8 wf[16];
    {
        const float* wp0 = phi_w + (size_t)(l0 + r) * NC + q * 8;
        #pragma unroll
        for (int it = 0; it < 16; it++) {
            float4 x = *(const float4*)(wp0 + it * 32);
            float4 y = *(const float4*)(wp0 + it * 32 + 4);
            bf16x8 t;
            t[0] = (short)f2bf(x.x); t[1] = (short)f2bf(x.y);
            t[2] = (short)f2bf(x.z); t[3] = (short)f2bf(x.w);
            t[4] = (short)f2bf(y.x); t[5] = (short)f2bf(y.y);
            t[6] = (short)f2bf(y.z); t[7] = (short)f2bf(y.w);
            wf[it] = t;
        }
    }

    f32x4 acc2[4][4];
    #pragma unroll
    for (int fm = 0; fm < 4; fm++)
        #pragma unroll
        for (int fc = 0; fc < 4; fc++) acc2[fm][fc] = fz;
    float ssacc[4] = {0.f, 0.f, 0.f, 0.f};

    const float* kpb = key + (size_t)b * NC * NN + n0;

    for (int s = 0; s < NSUB; s++) {
        __syncthreads();   // prev GEMM2 done with Knc/Kcn/A1 before restage

        // ---- stage K sub-tile (coalesced f32 -> bf16 in two layouts) ----
        const float* kp = kpb + s * NT;
        for (int idx = tid; idx < NC * (NT / 4); idx += 512) {
            int c = idx >> 4;
            int j = (idx & 15) << 2;
            float4 v = *(const float4*)(kp + (size_t)c * NN + j);
            unsigned short b0 = f2bf(v.x), b1 = f2bf(v.y), b2 = f2bf(v.z), b3 = f2bf(v.w);
            uint32_t* dst = (uint32_t*)&Kcn[c * 72 + j];
            dst[0] = (uint32_t)b0 | ((uint32_t)b1 << 16);
            dst[1] = (uint32_t)b2 | ((uint32_t)b3 << 16);
            Knc[(j + 0) * 520 + c] = b0;
            Knc[(j + 1) * 520 + c] = b1;
            Knc[(j + 2) * 520 + c] = b2;
            Knc[(j + 3) * 520 + c] = b3;
        }
        __syncthreads();

        // ---- GEMM1: a1 = W(64x512) @ Ktile(512x64) ----
        {
            f32x4 acc0 = fz, acc1 = fz;
            #pragma unroll
            for (int it = 0; it < 16; it++) {
                int kc = it * 32;
                bf16x8 b0 = *(const bf16x8*)&Knc[(nc0 + r) * 520 + kc + q * 8];
                bf16x8 b1 = *(const bf16x8*)&Knc[(nc0 + 16 + r) * 520 + kc + q * 8];
                acc0 = __builtin_amdgcn_mfma_f32_16x16x32_bf16(wf[it], b0, acc0, 0, 0, 0);
                acc1 = __builtin_amdgcn_mfma_f32_16x16x32_bf16(wf[it], b1, acc1, 0, 0, 0);
            }
            #pragma unroll
            for (int i = 0; i < 4; i++) {
                int l = l0 + q * 4 + i;
                float scl = sc[l], shf = sh[l];
                float v0 = fmaxf(acc0[i] * scl + shf, 0.f);
                float v1 = fmaxf(acc1[i] * scl + shf, 0.f);
                A1[l * 72 + nc0 + r]      = f2bf(v0);
                A1[l * 72 + nc0 + 16 + r] = f2bf(v1);
                ssacc[i] += v0 * v0 + v1 * v1;
            }
        }
        __syncthreads();

        // ---- GEMM2: acc2 += a1(64xNT) @ Ktile^T(NTx512) ----
        #pragma unroll
        for (int kn = 0; kn < NT; kn += 32) {
            bf16x8 a[4];
            #pragma unroll
            for (int fm = 0; fm < 4; fm++)
                a[fm] = *(const bf16x8*)&A1[(fm * 16 + r) * 72 + kn + q * 8];
            #pragma unroll
            for (int fc = 0; fc < 4; fc++) {
                bf16x8 bb = *(const bf16x8*)&Kcn[(c0 + fc * 16 + r) * 72 + kn + q * 8];
                #pragma unroll
                for (int fm = 0; fm < 4; fm++)
                    acc2[fm][fc] = __builtin_amdgcn_mfma_f32_16x16x32_bf16(a[fm], bb, acc2[fm][fc], 0, 0, 0);
            }
        }
    }

    // ---- ssq: reduce over r, one atomic per (wave, i) ----
    #pragma unroll
    for (int i = 0; i < 4; i++) {
        float s = ssacc[i];
        s += __shfl_xor(s, 1);
        s += __shfl_xor(s, 2);
        s += __shfl_xor(s, 4);
        s += __shfl_xor(s, 8);
        if (r == 0) atomicAdd(&ssq[b * NL + l0 + q * 4 + i], s);
    }

    // ---- plain (non-atomic) partial store ----
    float* pp = part + ((size_t)chunk * NB + b) * (NL * NC);
    #pragma unroll
    for (int fm = 0; fm < 4; fm++)
        #pragma unroll
        for (int fc = 0; fc < 4; fc++)
            #pragma unroll
            for (int i = 0; i < 4; i++) {
                int l = fm * 16 + q * 4 + i;
                int c = c0 + fc * 16 + r;
                pp[l * NC + c] = acc2[fm][fc][i];
            }
}

// ---------------------------------------------------------------------------
// Kernel R: latu[b][l][c] = sum_s part[s][b][l][c]   (14 partials)
// ---------------------------------------------------------------------------
__global__ __launch_bounds__(256)
void kR(const float* __restrict__ part, float* __restrict__ latu) {
    size_t base = ((size_t)blockIdx.x * 256 + threadIdx.x) * 4;  // 262144 floats total
    float4 acc = {0.f, 0.f, 0.f, 0.f};
    #pragma unroll
    for (int s = 0; s < NCHUNK; s++) {
        float4 v = *(const float4*)(part + (size_t)s * (NB * NL * NC) + base);
        acc.x += v.x; acc.y += v.y; acc.z += v.z; acc.w += v.w;
    }
    *(float4*)(latu + base) = acc;
}

// ---------------------------------------------------------------------------
// Kernel B (one block per b): latent = latu/||.||_N ; ln = l2norm rows;
// aff = softmax(ln ln^T); latent2 = aff @ latent -> lat2T[b][c][l] bf16
// ---------------------------------------------------------------------------
__global__ __launch_bounds__(256, 1)
void kB(const float* __restrict__ latu, const float* __restrict__ ssq,
        unsigned short* __restrict__ lat2T) {
    extern __shared__ char smem[];
    unsigned short* Lb = (unsigned short*)smem;             // [64][520]
    unsigned short* Lt = (unsigned short*)(smem + 66560);   // [512][72]
    float* aff = (float*)(smem + 140288);                   // [64][68]
    float* inv_nl = (float*)(smem + 157696);
    float* s_c = inv_nl + 64;

    const int tid = threadIdx.x;
    const int b = blockIdx.x;

    if (tid < 64) {
        float s = ssq[b * NL + tid];
        inv_nl[tid] = 1.f / fmaxf(sqrtf(s), 1e-12f);
    }
    __syncthreads();

    const float* lu = latu + (size_t)b * NL * NC;
    for (int idx = tid; idx < NL * (NC / 4); idx += 256) {
        int l = idx >> 7;
        int c = (idx & 127) << 2;
        float4 v = *(const float4*)(lu + l * NC + c);
        float inv = inv_nl[l];
        unsigned short b0 = f2bf(v.x * inv), b1 = f2bf(v.y * inv);
        unsigned short b2 = f2bf(v.z * inv), b3 = f2bf(v.w * inv);
        uint32_t* d = (uint32_t*)&Lb[l * 520 + c];
        d[0] = (uint32_t)b0 | ((uint32_t)b1 << 16);
        d[1] = (uint32_t)b2 | ((uint32_t)b3 << 16);
        Lt[(c + 0) * 72 + l] = b0;
        Lt[(c + 1) * 72 + l] = b1;
        Lt[(c + 2) * 72 + l] = b2;
        Lt[(c + 3) * 72 + l] = b3;
    }
    __syncthreads();

    // row norms of latent (over C)
    {
        int l = tid >> 2, p = tid & 3;
        float s = 0.f;
        for (int c = p * 128; c < p * 128 + 128; c += 4) {
            const unsigned short* d = &Lb[l * 520 + c];
            float v0 = bf2f(d[0]), v1 = bf2f(d[1]), v2 = bf2f(d[2]), v3 = bf2f(d[3]);
            s += v0 * v0 + v1 * v1 + v2 * v2 + v3 * v3;
        }
        s += __shfl_xor(s, 1);
        s += __shfl_xor(s, 2);
        if (p == 0) s_c[l] = 1.f / fmaxf(sqrtf(s), 1e-12f);
    }
    __syncthreads();

    const int w = tid >> 6, lane = tid & 63, q = lane >> 4, r = lane & 15;
    const f32x4 fz = {0.f, 0.f, 0.f, 0.f};

    // G = lat @ lat^T -> logits into aff
    {
        f32x4 g[4];
        #pragma unroll
        for (int fm = 0; fm < 4; fm++) g[fm] = fz;
        for (int kc = 0; kc < NC; kc += 32) {
            bf16x8 a = *(const bf16x8*)&Lb[(w * 16 + r) * 520 + kc + q * 8];
            #pragma unroll
            for (int fm = 0; fm < 4; fm++) {
                bf16x8 bb = *(const bf16x8*)&Lb[(fm * 16 + r) * 520 + kc + q * 8];
                g[fm] = __builtin_amdgcn_mfma_f32_16x16x32_bf16(a, bb, g[fm], 0, 0, 0);
            }
        }
        #pragma unroll
        for (int fm = 0; fm < 4; fm++)
            #pragma unroll
            for (int i = 0; i < 4; i++) {
                int l = w * 16 + q * 4 + i;
                int m = fm * 16 + r;
                aff[l * 68 + m] = g[fm][i] * s_c[l] * s_c[m];
            }
    }
    __syncthreads();

    // softmax over rows of aff (4 threads per row)
    {
        int l = tid >> 2, p = tid & 3;
        float e[16];
        float mx = -1e30f;
        #pragma unroll
        for (int k = 0; k < 16; k++) mx = fmaxf(mx, aff[l * 68 + p * 16 + k]);
        mx = fmaxf(mx, __shfl_xor(mx, 1));
        mx = fmaxf(mx, __shfl_xor(mx, 2));
        float s = 0.f;
        #pragma unroll
        for (int k = 0; k < 16; k++) { e[k] = __expf(aff[l * 68 + p * 16 + k] - mx); s += e[k]; }
        s += __shfl_xor(s, 1);
        s += __shfl_xor(s, 2);
        float invs = 1.f / s;
        __syncthreads();   // all logit reads done before overwrite
        #pragma unroll
        for (int k = 0; k < 16; k++) aff[l * 68 + p * 16 + k] = e[k] * invs;
    }
    __syncthreads();

    // latent2 = aff(64x64) @ lat(64x512); write lat2T[b][c][l] bf16
    {
        f32x4 acc[4][8];
        #pragma unroll
        for (int fm = 0; fm < 4; fm++)
            #pragma unroll
            for (int fc = 0; fc < 8; fc++) acc[fm][fc] = fz;
        #pragma unroll
        for (int km = 0; km < 64; km += 32) {
            bf16x8 a[4];
            #pragma unroll
            for (int fm = 0; fm < 4; fm++) {
                const float* ap = &aff[(fm * 16 + r) * 68 + km + q * 8];
                float4 x = *(const float4*)ap;
                float4 y = *(const float4*)(ap + 4);
                bf16x8 t;
                t[0] = (short)f2bf(x.x); t[1] = (short)f2bf(x.y);
                t[2] = (short)f2bf(x.z); t[3] = (short)f2bf(x.w);
                t[4] = (short)f2bf(y.x); t[5] = (short)f2bf(y.y);
                t[6] = (short)f2bf(y.z); t[7] = (short)f2bf(y.w);
                a[fm] = t;
            }
            #pragma unroll
            for (int fc = 0; fc < 8; fc++) {
                bf16x8 bb = *(const bf16x8*)&Lt[(w * 128 + fc * 16 + r) * 72 + km + q * 8];
                #pragma unroll
                for (int fm = 0; fm < 4; fm++)
                    acc[fm][fc] = __builtin_amdgcn_mfma_f32_16x16x32_bf16(a[fm], bb, acc[fm][fc], 0, 0, 0);
            }
        }
        unsigned short* out = lat2T + (size_t)b * NC * NL;
        #pragma unroll
        for (int fm = 0; fm < 4; fm++)
            #pragma unroll
            for (int fc = 0; fc < 8; fc++)
                #pragma unroll
                for (int i = 0; i < 4; i++) {
                    int l = fm * 16 + q * 4 + i;
                    int c = w * 128 + fc * 16 + r;
                    out[c * 64 + l] = f2bf(acc[fm][fc][i]);
                }
    }
}

// ---------------------------------------------------------------------------
// Kernel C: per (b, n-tile): a2 = relu(BN(Wp @ Qtile)); col-l2norm over L;
//           out[c][n] = latent2^T(512x64) @ a2(64xNT)
// ---------------------------------------------------------------------------
__global__ __launch_bounds__(256, 2)
void kC(const float* __restrict__ query, const float* __restrict__ phip_w,
        const float* __restrict__ gma, const float* __restrict__ bta,
        const float* __restrict__ mu, const float* __restrict__ var,
        const unsigned short* __restrict__ lat2T, float* __restrict__ out) {
    extern __shared__ char smem[];
    unsigned short* Qnc = (unsigned short*)smem;             // [NT][520]
    unsigned short* A2T = (unsigned short*)(smem + 66560);   // [NT][72]
    float* sc = (float*)(smem + 75776);
    float* sh = sc + NL;

    const int tid = threadIdx.x;
    const int b = blockIdx.y;
    const int n0 = blockIdx.x * NT;

    if (tid < NL) {
        float s = gma[tid] * rsqrtf(var[tid] + 1e-5f);
        sc[tid] = s;
        sh[tid] = bta[tid] - mu[tid] * s;
    }

    const float* qp = query + (size_t)b * NC * NN + n0;
    for (int idx = tid; idx < NC * (NT / 4); idx += 256) {
        int c = idx >> 4;
        int j = (idx & 15) << 2;
        float4 v = *(const float4*)(qp + (size_t)c * NN + j);
        Qnc[(j + 0) * 520 + c] = f2bf(v.x);
        Qnc[(j + 1) * 520 + c] = f2bf(v.y);
        Qnc[(j + 2) * 520 + c] = f2bf(v.z);
        Qnc[(j + 3) * 520 + c] = f2bf(v.w);
    }
    __syncthreads();

    const int w = tid >> 6, lane = tid & 63, q = lane >> 4, r = lane & 15;
    const f32x4 fz = {0.f, 0.f, 0.f, 0.f};

    // GEMM1: a2T[n][l] = Qtile^T @ Wp^T ; wave w: n rows [w*16, w*16+16)
    {
        f32x4 acc[4];
        #pragma unroll
        for (int fl = 0; fl < 4; fl++) acc[fl] = fz;
        float scv[4], shv[4];
        #pragma unroll
        for (int fl = 0; fl < 4; fl++) { scv[fl] = sc[fl * 16 + r]; shv[fl] = sh[fl * 16 + r]; }
        for (int kc = 0; kc < NC; kc += 32) {
            bf16x8 a = *(const bf16x8*)&Qnc[(w * 16 + r) * 520 + kc + q * 8];
            #pragma unroll
            for (int fl = 0; fl < 4; fl++) {
                const float* wp = phip_w + (size_t)(fl * 16 + r) * NC + kc + q * 8;
                float4 x = *(const float4*)wp;
                float4 y = *(const float4*)(wp + 4);
                bf16x8 t;
                t[0] = (short)f2bf(x.x); t[1] = (short)f2bf(x.y);
                t[2] = (short)f2bf(x.z); t[3] = (short)f2bf(x.w);
                t[4] = (short)f2bf(y.x); t[5] = (short)f2bf(y.y);
                t[6] = (short)f2bf(y.z); t[7] = (short)f2bf(y.w);
                acc[fl] = __builtin_amdgcn_mfma_f32_16x16x32_bf16(a, t, acc[fl], 0, 0, 0);
            }
        }
        float v[4][4];
        float ssum[4] = {0.f, 0.f, 0.f, 0.f};
        #pragma unroll
        for (int fl = 0; fl < 4; fl++)
            #pragma unroll
            for (int i = 0; i < 4; i++) {
                float x = fmaxf(acc[fl][i] * scv[fl] + shv[fl], 0.f);
                v[fl][i] = x;
                ssum[i] += x * x;
            }
        #pragma unroll
        for (int i = 0; i < 4; i++) {
            float s = ssum[i];
            s += __shfl_xor(s, 1);
            s += __shfl_xor(s, 2);
            s += __shfl_xor(s, 4);
            s += __shfl_xor(s, 8);
            float inv = 1.f / fmaxf(sqrtf(s), 1e-12f);
            int n = w * 16 + q * 4 + i;
            #pragma unroll
            for (int fl = 0; fl < 4; fl++)
                A2T[n * 72 + fl * 16 + r] = f2bf(v[fl][i] * inv);
        }
    }
    __syncthreads();

    // GEMM3: out[c][n] = lat2T(512x64) @ a2(64xNT)
    const unsigned short* Ab = lat2T + (size_t)b * NC * NL;
    float* op = out + (size_t)b * NC * NN + n0;
    for (int half = 0; half < 2; half++) {
        int cb = w * 128 + half * 64;
        f32x4 acc[4][4];
        #pragma unroll
        for (int fm = 0; fm < 4; fm++)
            #pragma unroll
            for (int fn = 0; fn < 4; fn++) acc[fm][fn] = fz;
        #pragma unroll
        for (int kl = 0; kl < 64; kl += 32) {
            bf16x8 a[4];
            #pragma unroll
            for (int fm = 0; fm < 4; fm++)
                a[fm] = *(const bf16x8*)&Ab[(size_t)(cb + fm * 16 + r) * 64 + kl + q * 8];
            #pragma unroll
            for (int fn = 0; fn < 4; fn++) {
                bf16x8 bb = *(const bf16x8*)&A2T[(fn * 16 + r) * 72 + kl + q * 8];
                #pragma unroll
                for (int fm = 0; fm < 4; fm++)
                    acc[fm][fn] = __builtin_amdgcn_mfma_f32_16x16x32_bf16(a[fm], bb, acc[fm][fn], 0, 0, 0);
            }
        }
        #pragma unroll
        for (int fm = 0; fm < 4; fm++)
            #pragma unroll
            for (int fn = 0; fn < 4; fn++)
                #pragma unroll
                for (int i = 0; i < 4; i++) {
                    int c = cb + fm * 16 + q * 4 + i;
                    int n = fn * 16 + r;
                    op[(size_t)c * NN + n] = acc[fm][fn][i];
                }
    }
}

// ---------------------------------------------------------------------------
extern "C" void kernel_launch(void* const* d_in, const int* in_sizes, int n_in,
                              void* d_out, int out_size, void* d_ws, size_t ws_size,
                              hipStream_t stream) {
    (void)in_sizes; (void)n_in; (void)out_size; (void)ws_size;
    const float* query = (const float*)d_in[0];
    const float* key   = (const float*)d_in[1];
    const float* phi_w = (const float*)d_in[2];
    const float* phi_g = (const float*)d_in[3];
    const float* phi_b = (const float*)d_in[4];
    const float* phi_m = (const float*)d_in[5];
    const float* phi_v = (const float*)d_in[6];
    const float* php_w = (const float*)d_in[7];
    const float* php_g = (const float*)d_in[8];
    const float* php_b = (const float*)d_in[9];
    const float* php_m = (const float*)d_in[10];
    const float* php_v = (const float*)d_in[11];
    float* out = (float*)d_out;

    char* ws = (char*)d_ws;
    float* part = (float*)ws;                                  // 14*8*64*512*4 = 14,680,064 B
    float* ssq  = (float*)(ws + 14680064);                     // 2048 B
    float* latu = (float*)(ws + 14682112);                     // 1,048,576 B
    unsigned short* lat2T = (unsigned short*)(ws + 15730688);  // 524,288 B

    hipFuncSetAttribute((const void*)kA, hipFuncAttributeMaxDynamicSharedMemorySize, 150016);
    hipFuncSetAttribute((const void*)kB, hipFuncAttributeMaxDynamicSharedMemorySize, 158208);
    hipFuncSetAttribute((const void*)kC, hipFuncAttributeMaxDynamicSharedMemorySize, 76288);

    hipMemsetAsync(ssq, 0, 2048, stream);

    kA<<<dim3(NCHUNK, NB), 512, 150016, stream>>>(key, phi_w, phi_g, phi_b, phi_m, phi_v, part, ssq);
    kR<<<dim3(256), 256, 0, stream>>>(part, latu);
    kB<<<dim3(NB), 256, 158208, stream>>>(latu, ssq, lat2T);
    kC<<<dim3(NTILES, NB), 256, 76288, stream>>>(query, php_w, php_g, php_b, php_m, php_v, lat2T, out);
}